// Round 12
// baseline (11165.898 us; speedup 1.0000x reference)
//
#include <hip/hip_runtime.h>

#define NB 64
#define NT 1024
#define DIN 12
#define NH 256
#define NG 1024
#define NCLS 17
#define TCL 128
#define NCHUNK 8
#define XPS ((size_t)2 * NB * TCL * NG)   // floats per xp1 chunk buffer

typedef _Float16 f16;
typedef __attribute__((ext_vector_type(2))) _Float16 half2_t;
typedef __attribute__((ext_vector_type(8))) _Float16 f16x8;
typedef __attribute__((ext_vector_type(4))) float f32x4;
typedef unsigned int uint;
typedef unsigned short ushort;

struct U4 { uint x, y, z, w; };

__device__ __forceinline__ float sigm(float v) { return 1.0f / (1.0f + __expf(-v)); }
__device__ __forceinline__ float tanh_(float v) {
    v = fminf(fmaxf(v, -15.0f), 15.0f);
    float e = __expf(2.0f * v);
    return (e - 1.0f) / (e + 1.0f);
}
__device__ __forceinline__ float dot2(uint w, uint h, float c) {
    return __builtin_amdgcn_fdot2(__builtin_bit_cast(half2_t, w),
                                  __builtin_bit_cast(half2_t, h), c, false);
}
__device__ __forceinline__ uint pack16(float a, float b) {
    union { f16 h[2]; uint u; } cv; cv.h[0] = (f16)a; cv.h[1] = (f16)b; return cv.u;
}
__device__ __forceinline__ uint pkrtz(float a, float b) {
    return __builtin_bit_cast(uint, __builtin_amdgcn_cvt_pkrtz(a, b));
}
__device__ __forceinline__ ushort hbits(f16 v) {
    union { f16 h; ushort u; } cv; cv.h = v; return cv.u;
}
__device__ __forceinline__ uint rdlane(uint v, int l) {
    return (uint)__builtin_amdgcn_readlane((int)v, l);
}

// ---------------------------------------------------------------------------
// Broadcast + dot machinery (comp-major over 8 accumulators). R4 verbatim.
// ---------------------------------------------------------------------------
#define RDL4(HV, G, S0, S1, S2, S3)                                           \
    uint S0 = rdlane((HV).x, (G)), S1 = rdlane((HV).y, (G)),                  \
         S2 = rdlane((HV).z, (G)), S3 = rdlane((HV).w, (G))

#define DOTS_GRP(AH, BH, W0, W1, W2, W3, S0, S1, S2, S3) do {                 \
    AH[0] = dot2((W0).x, (S0), AH[0]); AH[1] = dot2((W1).x, (S0), AH[1]);     \
    AH[2] = dot2((W2).x, (S0), AH[2]); AH[3] = dot2((W3).x, (S0), AH[3]);     \
    BH[0] = dot2((W0).y, (S1), BH[0]); BH[1] = dot2((W1).y, (S1), BH[1]);     \
    BH[2] = dot2((W2).y, (S1), BH[2]); BH[3] = dot2((W3).y, (S1), BH[3]);     \
    AH[0] = dot2((W0).z, (S2), AH[0]); AH[1] = dot2((W1).z, (S2), AH[1]);     \
    AH[2] = dot2((W2).z, (S2), AH[2]); AH[3] = dot2((W3).z, (S2), AH[3]);     \
    BH[0] = dot2((W0).w, (S3), BH[0]); BH[1] = dot2((W1).w, (S3), BH[1]);     \
    BH[2] = dot2((W2).w, (S3), BH[2]); BH[3] = dot2((W3).w, (S3), BH[3]);     \
} while (0)

#define PIN4(W) asm volatile("" : "+v"((W).x), "+v"((W).y), "+v"((W).z), "+v"((W).w))

// ---------------------------------------------------------------------------
// k_prep: k-split packing (R4 layout, unchanged).
// Wk{0,1}n [dir][q][m 0..15][t512] uint4; lane t512=(u,kh) holds
// w_hh[dir][q*256+u][2*kp..2*kp+1] for kp = kh*64+4m+c, c=0..3.
// ---------------------------------------------------------------------------
__global__ void k_prep(const float* __restrict__ w_hh0, const float* __restrict__ w_hh1,
                       const float* __restrict__ w_ih0, const float* __restrict__ w_ih1,
                       const float* __restrict__ b_ih1, const float* __restrict__ b_hh1,
                       uint* __restrict__ Wk0n, uint* __restrict__ wih0n,
                       uint* __restrict__ Wk1n,
                       f16* __restrict__ wih1h, float* __restrict__ bsum1) {
    int i = blockIdx.x * 256 + threadIdx.x;
    if (i < 262144) {                      // Wk0n
        int c = i & 3; int r = i >> 2;
        int t512 = r & 511; int s = r >> 9;
        int m = s & 15, q = (s >> 4) & 3, dir = s >> 6;
        int u = t512 & 255, kh = t512 >> 8;
        int kp = kh * 64 + 4 * m + c;
        const float* row = w_hh0 + (size_t)dir * NG * NH + (size_t)(q * 256 + u) * NH;
        Wk0n[i] = pack16(row[2 * kp], row[2 * kp + 1]);
    }
    if (i < 262144) {                      // Wk1n
        int c = i & 3; int r = i >> 2;
        int t512 = r & 511; int s = r >> 9;
        int m = s & 15, q = (s >> 4) & 3, dir = s >> 6;
        int u = t512 & 255, kh = t512 >> 8;
        int kp = kh * 64 + 4 * m + c;
        const float* row = w_hh1 + (size_t)dir * NG * NH + (size_t)(q * 256 + u) * NH;
        Wk1n[i] = pack16(row[2 * kp], row[2 * kp + 1]);
    }
    if (i < 12288) {                       // wih0n: [dir][g2*6+dp][t512]
        int t512 = i & 511; int r = i >> 9;
        int dp = r % 6, g2 = (r / 6) & 1, dir = r / 12;
        int q = 2 * (t512 >> 8) + g2, u = t512 & 255;
        const float* row = w_ih0 + ((size_t)dir * NG + q * 256 + u) * DIN;
        wih0n[i] = pack16(row[2 * dp], row[2 * dp + 1]);
    }
    if (i < 2 * NG * 2 * NH) wih1h[i] = (f16)w_ih1[i];
    if (i < 2 * NG) bsum1[i] = b_ih1[i] + b_hh1[i];
}

// ---------------------------------------------------------------------------
// rec0_seq (round 12): R4 body + 2 BATCHES PER BLOCK. 64 blocks, each block
// owns (dir, b0=2bp, b1=2bp+1). The weight stream (12 groups from L2, 4 from
// LDS, wih regs) is fetched ONCE per step and consumed by both batches —
// per-XCD L2 traffic halves while the doubled dot work is independent ILP.
// Everything else (k-split kh halves, zb exchange, late out0h store) = R4.
// ---------------------------------------------------------------------------
__device__ void rec0_seq(char* smem, int rb,
                         const uint* __restrict__ Wk0n, const uint* __restrict__ wih0n,
                         const float* __restrict__ b_ih0, const float* __restrict__ b_hh0,
                         const float* __restrict__ x, f16* __restrict__ out0h,
                         float* __restrict__ hst, float* __restrict__ cst) {
    uint4* wlds4 = (uint4*)smem;                         // [4 q][4 mm][512] uint4 = 128 KB
    ushort* hs0 = (ushort*)(smem + 131072);              // [2 par][256] f16
    ushort* hs1 = (ushort*)(smem + 132096);              // [2 par][256] f16
    float4* zb0 = (float4*)(smem + 133120);              // [256] float4
    float4* zb1 = (float4*)(smem + 137216);              // [256] float4

    const int tid = threadIdx.x;
    const int dir = rb >> 5;
    const int bp = rb & 31;
    const int b0 = bp * 2, b1 = b0 + 1;
    const int u = tid & 255;
    const int kh = tid >> 8;
    const uint4* W4 = (const uint4*)Wk0n;

    #pragma unroll
    for (int q = 0; q < 4; ++q)
        #pragma unroll
        for (int mm = 0; mm < 4; ++mm)
            wlds4[(q * 4 + mm) * 512 + tid] =
                W4[((size_t)(dir * 4 + q) * 16 + 12 + mm) * 512 + tid];

    U4 wr[4][12];
    #pragma unroll
    for (int q = 0; q < 4; ++q)
        #pragma unroll
        for (int m = 0; m < 12; ++m) {
            uint4 t = W4[((size_t)(dir * 4 + q) * 16 + m) * 512 + tid];
            wr[q][m].x = t.x; wr[q][m].y = t.y; wr[q][m].z = t.z; wr[q][m].w = t.w;
        }
    #pragma unroll
    for (int q = 0; q < 4; ++q)
        #pragma unroll
        for (int m = 0; m < 12; ++m) PIN4(wr[q][m]);

    uint wih[12];
    float bias2[2];
    #pragma unroll
    for (int g2 = 0; g2 < 2; ++g2) {
        const int q = 2 * kh + g2;
        bias2[g2] = b_ih0[dir * NG + q * 256 + u] + b_hh0[dir * NG + q * 256 + u];
        #pragma unroll
        for (int dp = 0; dp < 6; ++dp)
            wih[g2 * 6 + dp] = wih0n[(dir * 12 + g2 * 6 + dp) * 512 + tid];
    }

    const int sidx0 = (dir * NB + b0) * NH + u;
    const int sidx1 = (dir * NB + b1) * NH + u;
    const int seg = kh * 16 + (tid & 15);
    const bool storer = (tid & 255) < 16;
    float cv0 = 0.f, hv0 = 0.f, cv1 = 0.f, hv1 = 0.f;
    if (tid < 256) { hs0[tid] = 0; hs1[tid] = 0; }

    const float4* xb0 = (const float4*)(x + ((size_t)b0 * NT + (dir ? NT - 1 : 0)) * DIN);
    const float4* xb1 = (const float4*)(x + ((size_t)b1 * NT + (dir ? NT - 1 : 0)) * DIN);
    const long xstep = dir ? -3 : 3;            // float4 stride per timestep
    float4 xA0 = xb0[0], xB0 = xb0[1], xC0 = xb0[2];
    float4 xA1 = xb1[0], xB1 = xb1[1], xC1 = xb1[2];
    __syncthreads();

    #pragma unroll 1
    for (int it = 0; it < NT; ++it) {
        const int par = it & 1;
        uint4 hvv0 = ((const uint4*)(hs0 + par * 256))[seg];
        uint4 hvv1 = ((const uint4*)(hs1 + par * 256))[seg];

        // store h(it-1) for both batches (ack drains under the dot stream)
        if (it > 0 && storer) {
            const int tprev = dir ? (NT - it) : (it - 1);
            *(uint4*)(out0h + ((size_t)b0 * NT + tprev) * 512 + dir * 256 + seg * 8) = hvv0;
            *(uint4*)(out0h + ((size_t)b1 * NT + tprev) * 512 + dir * 256 + seg * 8) = hvv1;
        }

        // prefetch next step's x (both batches)
        const long xo = (it + 1 < NT) ? (long)(it + 1) * xstep : (long)it * xstep;
        float4 xA0n = xb0[xo], xB0n = xb0[xo + 1], xC0n = xb0[xo + 2];
        float4 xA1n = xb1[xo], xB1n = xb1[xo + 1], xC1n = xb1[xo + 2];

        uint xph0[6] = {pkrtz(xA0.x, xA0.y), pkrtz(xA0.z, xA0.w), pkrtz(xB0.x, xB0.y),
                        pkrtz(xB0.z, xB0.w), pkrtz(xC0.x, xC0.y), pkrtz(xC0.z, xC0.w)};
        uint xph1[6] = {pkrtz(xA1.x, xA1.y), pkrtz(xA1.z, xA1.w), pkrtz(xB1.x, xB1.y),
                        pkrtz(xB1.z, xB1.w), pkrtz(xC1.x, xC1.y), pkrtz(xC1.z, xC1.w)};
        float xz00 = bias2[0], xz01 = bias2[1];   // batch0: lane's 2 gates
        float xz10 = bias2[0], xz11 = bias2[1];   // batch1
        #pragma unroll
        for (int d = 0; d < 6; ++d) {
            xz00 = dot2(wih[d], xph0[d], xz00);
            xz01 = dot2(wih[6 + d], xph0[d], xz01);
            xz10 = dot2(wih[d], xph1[d], xz10);
            xz11 = dot2(wih[6 + d], xph1[d], xz11);
        }

        float ahA0[4] = {0.f, 0.f, 0.f, 0.f};
        float ahB0[4] = {0.f, 0.f, 0.f, 0.f};
        float ahA1[4] = {0.f, 0.f, 0.f, 0.f};
        float ahB1[4] = {0.f, 0.f, 0.f, 0.f};

        #pragma unroll
        for (int g = 0; g < 12; ++g) {
            RDL4(hvv0, g, s00, s01, s02, s03);
            DOTS_GRP(ahA0, ahB0, wr[0][g], wr[1][g], wr[2][g], wr[3][g],
                     s00, s01, s02, s03);
            RDL4(hvv1, g, s10, s11, s12, s13);
            DOTS_GRP(ahA1, ahB1, wr[0][g], wr[1][g], wr[2][g], wr[3][g],
                     s10, s11, s12, s13);
        }
        #pragma unroll
        for (int gg = 0; gg < 4; ++gg) {
            uint4 l0 = wlds4[(0 * 4 + gg) * 512 + tid];
            uint4 l1 = wlds4[(1 * 4 + gg) * 512 + tid];
            uint4 l2 = wlds4[(2 * 4 + gg) * 512 + tid];
            uint4 l3 = wlds4[(3 * 4 + gg) * 512 + tid];
            RDL4(hvv0, 12 + gg, s00, s01, s02, s03);
            DOTS_GRP(ahA0, ahB0, l0, l1, l2, l3, s00, s01, s02, s03);
            RDL4(hvv1, 12 + gg, s10, s11, s12, s13);
            DOTS_GRP(ahA1, ahB1, l0, l1, l2, l3, s10, s11, s12, s13);
        }

        float p00 = ahA0[0] + ahB0[0], p01 = ahA0[1] + ahB0[1];
        float p02 = ahA0[2] + ahB0[2], p03 = ahA0[3] + ahB0[3];
        float p10 = ahA1[0] + ahB1[0], p11 = ahA1[1] + ahB1[1];
        float p12 = ahA1[2] + ahB1[2], p13 = ahA1[3] + ahB1[3];
        if (kh == 0) { p00 += xz00; p01 += xz01; p10 += xz10; p11 += xz11; }
        else         { p02 += xz00; p03 += xz01; p12 += xz10; p13 += xz11; }

        if (kh) {
            zb0[u] = (float4){p00, p01, p02, p03};
            zb1[u] = (float4){p10, p11, p12, p13};
        }
        __syncthreads();                          // A: partials visible
        if (!kh) {
            float4 zp0 = zb0[u];
            float z0 = p00 + zp0.x, z1 = p01 + zp0.y;
            float z2 = p02 + zp0.z, z3 = p03 + zp0.w;
            cv0 = sigm(z1) * cv0 + sigm(z0) * tanh_(z2);
            hv0 = sigm(z3) * tanh_(cv0);
            hs0[(par ^ 1) * 256 + u] = hbits((f16)hv0);
            float4 zp1 = zb1[u];
            z0 = p10 + zp1.x; z1 = p11 + zp1.y;
            z2 = p12 + zp1.z; z3 = p13 + zp1.w;
            cv1 = sigm(z1) * cv1 + sigm(z0) * tanh_(z2);
            hv1 = sigm(z3) * tanh_(cv1);
            hs1[(par ^ 1) * 256 + u] = hbits((f16)hv1);
        }
        __syncthreads();                          // B: new h visible
        xA0 = xA0n; xB0 = xB0n; xC0 = xC0n;
        xA1 = xA1n; xB1 = xB1n; xC1 = xC1n;
    }

    // epilogue: store h(NT-1) for both batches
    if (storer) {
        uint4 hvf0 = ((const uint4*)(hs0 + 0 * 256))[seg];
        uint4 hvf1 = ((const uint4*)(hs1 + 0 * 256))[seg];
        const int tlast = dir ? 0 : (NT - 1);
        *(uint4*)(out0h + ((size_t)b0 * NT + tlast) * 512 + dir * 256 + seg * 8) = hvf0;
        *(uint4*)(out0h + ((size_t)b1 * NT + tlast) * 512 + dir * 256 + seg * 8) = hvf1;
    }
    if (!kh) {
        cst[sidx0] = cv0; hst[sidx0] = hv0;
        cst[sidx1] = cv1; hst[sidx1] = hv1;
    }
}

// ---------------------------------------------------------------------------
// rec1_seq: 2-batch twin of rec0 (xq gate inputs from xp1 instead of x-proj).
// ---------------------------------------------------------------------------
__device__ void rec1_seq(char* smem, int rb, int chunk, int nsteps,
                         const uint* __restrict__ Wk1n, const float* __restrict__ xp1,
                         float* __restrict__ hst, float* __restrict__ cst,
                         float* __restrict__ hsm) {
    uint4* wlds4 = (uint4*)smem;                         // 128 KB
    ushort* hs0 = (ushort*)(smem + 131072);
    ushort* hs1 = (ushort*)(smem + 132096);
    float4* zb0 = (float4*)(smem + 133120);
    float4* zb1 = (float4*)(smem + 137216);

    const int tid = threadIdx.x;
    const int dir = rb >> 5;
    const int bp = rb & 31;
    const int b0 = bp * 2, b1 = b0 + 1;
    const int u = tid & 255;
    const int kh = tid >> 8;
    const int ld = 2 + dir;
    const uint4* W4 = (const uint4*)Wk1n;

    #pragma unroll
    for (int q = 0; q < 4; ++q)
        #pragma unroll
        for (int mm = 0; mm < 4; ++mm)
            wlds4[(q * 4 + mm) * 512 + tid] =
                W4[((size_t)(dir * 4 + q) * 16 + 12 + mm) * 512 + tid];

    U4 wr[4][12];
    #pragma unroll
    for (int q = 0; q < 4; ++q)
        #pragma unroll
        for (int m = 0; m < 12; ++m) {
            uint4 t = W4[((size_t)(dir * 4 + q) * 16 + m) * 512 + tid];
            wr[q][m].x = t.x; wr[q][m].y = t.y; wr[q][m].z = t.z; wr[q][m].w = t.w;
        }
    #pragma unroll
    for (int q = 0; q < 4; ++q)
        #pragma unroll
        for (int m = 0; m < 12; ++m) PIN4(wr[q][m]);

    const int sidx0 = (ld * NB + b0) * NH + u;
    const int sidx1 = (ld * NB + b1) * NH + u;
    const int seg = kh * 16 + (tid & 15);
    float cv0 = 0.f, hv0 = 0.f, hsv0 = 0.f;
    float cv1 = 0.f, hv1 = 0.f, hsv1 = 0.f;
    if (chunk > 0 && !kh) {
        cv0 = cst[sidx0]; hv0 = hst[sidx0];
        hsv0 = hsm[(dir * NB + b0) * NH + u];
        cv1 = cst[sidx1]; hv1 = hst[sidx1];
        hsv1 = hsm[(dir * NB + b1) * NH + u];
    }
    if (tid < 256) { hs0[tid] = hbits((f16)hv0); hs1[tid] = hbits((f16)hv1); }

    const float* xbase0 = xp1 + ((size_t)dir * NB + b0) * TCL * NG + u * 4;
    const float* xbase1 = xp1 + ((size_t)dir * NB + b1) * TCL * NG + u * 4;
    float4 xq0_cur = {0.f, 0.f, 0.f, 0.f};
    float4 xq1_cur = {0.f, 0.f, 0.f, 0.f};
    if (!kh) {
        xq0_cur = *(const float4*)xbase0;
        xq1_cur = *(const float4*)xbase1;
    }
    __syncthreads();

    #pragma unroll 1
    for (int it = 0; it < nsteps; ++it) {
        const int par = it & 1;
        uint4 hvv0 = ((const uint4*)(hs0 + par * 256))[seg];
        uint4 hvv1 = ((const uint4*)(hs1 + par * 256))[seg];

        // prefetch next step's gate inputs (full step of latency to hide)
        float4 xq0_nxt = xq0_cur, xq1_nxt = xq1_cur;
        if (!kh) {
            const int itn = (it + 1 < nsteps) ? (it + 1) : it;
            xq0_nxt = *(const float4*)(xbase0 + (size_t)itn * NG);
            xq1_nxt = *(const float4*)(xbase1 + (size_t)itn * NG);
        }

        float ahA0[4] = {0.f, 0.f, 0.f, 0.f};
        float ahB0[4] = {0.f, 0.f, 0.f, 0.f};
        float ahA1[4] = {0.f, 0.f, 0.f, 0.f};
        float ahB1[4] = {0.f, 0.f, 0.f, 0.f};

        #pragma unroll
        for (int g = 0; g < 12; ++g) {
            RDL4(hvv0, g, s00, s01, s02, s03);
            DOTS_GRP(ahA0, ahB0, wr[0][g], wr[1][g], wr[2][g], wr[3][g],
                     s00, s01, s02, s03);
            RDL4(hvv1, g, s10, s11, s12, s13);
            DOTS_GRP(ahA1, ahB1, wr[0][g], wr[1][g], wr[2][g], wr[3][g],
                     s10, s11, s12, s13);
        }
        #pragma unroll
        for (int gg = 0; gg < 4; ++gg) {
            uint4 l0 = wlds4[(0 * 4 + gg) * 512 + tid];
            uint4 l1 = wlds4[(1 * 4 + gg) * 512 + tid];
            uint4 l2 = wlds4[(2 * 4 + gg) * 512 + tid];
            uint4 l3 = wlds4[(3 * 4 + gg) * 512 + tid];
            RDL4(hvv0, 12 + gg, s00, s01, s02, s03);
            DOTS_GRP(ahA0, ahB0, l0, l1, l2, l3, s00, s01, s02, s03);
            RDL4(hvv1, 12 + gg, s10, s11, s12, s13);
            DOTS_GRP(ahA1, ahB1, l0, l1, l2, l3, s10, s11, s12, s13);
        }

        float p00 = ahA0[0] + ahB0[0], p01 = ahA0[1] + ahB0[1];
        float p02 = ahA0[2] + ahB0[2], p03 = ahA0[3] + ahB0[3];
        float p10 = ahA1[0] + ahB1[0], p11 = ahA1[1] + ahB1[1];
        float p12 = ahA1[2] + ahB1[2], p13 = ahA1[3] + ahB1[3];
        if (!kh) {
            p00 += xq0_cur.x; p01 += xq0_cur.y; p02 += xq0_cur.z; p03 += xq0_cur.w;
            p10 += xq1_cur.x; p11 += xq1_cur.y; p12 += xq1_cur.z; p13 += xq1_cur.w;
        }

        if (kh) {
            zb0[u] = (float4){p00, p01, p02, p03};
            zb1[u] = (float4){p10, p11, p12, p13};
        }
        __syncthreads();                          // A: partials visible
        if (!kh) {
            float4 zp0 = zb0[u];
            float z0 = p00 + zp0.x, z1 = p01 + zp0.y;
            float z2 = p02 + zp0.z, z3 = p03 + zp0.w;
            cv0 = sigm(z1) * cv0 + sigm(z0) * tanh_(z2);
            hv0 = sigm(z3) * tanh_(cv0);
            hsv0 += hv0;
            hs0[(par ^ 1) * 256 + u] = hbits((f16)hv0);
            float4 zp1 = zb1[u];
            z0 = p10 + zp1.x; z1 = p11 + zp1.y;
            z2 = p12 + zp1.z; z3 = p13 + zp1.w;
            cv1 = sigm(z1) * cv1 + sigm(z0) * tanh_(z2);
            hv1 = sigm(z3) * tanh_(cv1);
            hsv1 += hv1;
            hs1[(par ^ 1) * 256 + u] = hbits((f16)hv1);
        }
        __syncthreads();                          // B: new h visible
        xq0_cur = xq0_nxt; xq1_cur = xq1_nxt;
    }

    if (!kh) {
        cst[sidx0] = cv0; hst[sidx0] = hv0;
        hsm[(dir * NB + b0) * NH + u] = hsv0;
        cst[sidx1] = cv1; hst[sidx1] = hv1;
        hsm[(dir * NB + b1) * NH + u] = hsv1;
    }
}

// ---------------------------------------------------------------------------
// proj_role (chunk c): fp16 MFMA 16x16x32 direct-from-global. 512-thread
// blocks: 8 waves, each wave handles 1 m-tile. (R4 verbatim)
// ---------------------------------------------------------------------------
__device__ void proj_role(int pb, int c,
                          const f16* __restrict__ out0h, const f16* __restrict__ wih1h,
                          const float* __restrict__ bsum1, float* __restrict__ xp1) {
    const int tid = threadIdx.x;
    const int w = tid >> 6, l = tid & 63;
    const int lane16 = l & 15, quad = l >> 4;

    const int mtg = pb * 8 + w;                // 0..1023
    const int dirt = mtg >> 9;
    const int mtl = mtg & 511;

    const int ra = mtl * 16 + lane16;          // row over b(64) x tl(128)
    const int ab = ra >> 7, tla = ra & 127;
    const int ta = dirt ? (NT - 1 - c * TCL - tla) : (c * TCL + tla);
    const f16* Arow = out0h + ((size_t)ab * NT + ta) * 512 + quad * 8;

    uint4 afr[16];
    #pragma unroll
    for (int kt = 0; kt < 16; ++kt) afr[kt] = *(const uint4*)(Arow + kt * 32);

    int ob[4], otl[4];
    #pragma unroll
    for (int reg = 0; reg < 4; ++reg) {
        int rr = mtl * 16 + quad * 4 + reg;
        ob[reg] = rr >> 7; otl[reg] = rr & 127;
    }

    const f16* Bbase = wih1h + (size_t)dirt * NG * 512 + quad * 8;

    #pragma unroll 1
    for (int nt = 0; nt < 64; ++nt) {
        const int col = nt * 16 + lane16;
        const f16* Brow = Bbase + (size_t)col * 512;
        float bias = bsum1[dirt * NG + col];

        f32x4 acc = {0.f, 0.f, 0.f, 0.f};
        #pragma unroll
        for (int kt = 0; kt < 16; ++kt) {
            uint4 bv = *(const uint4*)(Brow + kt * 32);
            acc = __builtin_amdgcn_mfma_f32_16x16x32_f16(
                __builtin_bit_cast(f16x8, afr[kt]),
                __builtin_bit_cast(f16x8, bv), acc, 0, 0, 0);
        }
        const int ucol = col & 255, qcol = col >> 8;
        #pragma unroll
        for (int reg = 0; reg < 4; ++reg) {
            xp1[((size_t)(dirt * NB + ob[reg]) * TCL + otl[reg]) * NG
                + ucol * 4 + qcol] = acc[reg] + bias;
        }
    }
}

// ---------------------------------------------------------------------------
// Phase A: layer 0. 64 blocks x 512 threads (2 batches per block).
// ---------------------------------------------------------------------------
__global__ __launch_bounds__(512)
__attribute__((amdgpu_waves_per_eu(2, 2)))
void k_rec0(
    const uint* __restrict__ Wk0n, const uint* __restrict__ wih0n,
    const float* __restrict__ b_ih0, const float* __restrict__ b_hh0,
    const float* __restrict__ x, f16* __restrict__ out0h,
    float* __restrict__ hst, float* __restrict__ cst) {
    extern __shared__ __align__(16) char smem[];
    rec0_seq(smem, blockIdx.x, Wk0n, wih0n, b_ih0, b_hh0, x, out0h, hst, cst);
}

// ---------------------------------------------------------------------------
// Phase B launch j: blocks 0..63 = rec1 chunk j-1 (2 batches each); blocks
// 64..191 = proj chunk j. Double-buffered xp1.
// ---------------------------------------------------------------------------
__global__ __launch_bounds__(512)
__attribute__((amdgpu_waves_per_eu(2, 2)))
void k_pipe(
    int j,
    const uint* __restrict__ Wk1n,
    const f16* __restrict__ out0h, const f16* __restrict__ wih1h,
    const float* __restrict__ bsum1, float* __restrict__ xp1,
    float* __restrict__ hst, float* __restrict__ cst, float* __restrict__ hsm) {
    extern __shared__ __align__(16) char smem[];
    const int bid = blockIdx.x;
    if (bid < 64) {
        const int cc = j - 1;
        if (cc >= 0 && cc < NCHUNK)
            rec1_seq(smem, bid, cc, TCL, Wk1n,
                     xp1 + (size_t)(cc & 1) * XPS, hst, cst, hsm);
    } else {
        const int cp = j;
        if (cp < NCHUNK)
            proj_role(bid - 64, cp, out0h, wih1h, bsum1,
                      xp1 + (size_t)(cp & 1) * XPS);
    }
}

// ---------------------------------------------------------------------------
__global__ void k_fc(const float* __restrict__ hsm, const float* __restrict__ fc_w,
                     const float* __restrict__ fc_b, float* __restrict__ out) {
    const int b = blockIdx.x;
    const int n = threadIdx.x;
    if (n >= NCLS) return;
    float acc = fc_b[n];
    const float inv = 1.0f / (float)NT;
    for (int k = 0; k < 2 * NH; ++k) {
        float pv = hsm[((k >> 8) * NB + b) * NH + (k & 255)];
        acc += (pv * inv) * fc_w[n * 2 * NH + k];
    }
    out[b * NCLS + n] = acc;
}

// ---------------------------------------------------------------------------
extern "C" void kernel_launch(void* const* d_in, const int* in_sizes, int n_in,
                              void* d_out, int out_size, void* d_ws, size_t ws_size,
                              hipStream_t stream) {
    const float* x     = (const float*)d_in[0];
    const float* w_ih0 = (const float*)d_in[1];
    const float* w_hh0 = (const float*)d_in[2];
    const float* b_ih0 = (const float*)d_in[3];
    const float* b_hh0 = (const float*)d_in[4];
    const float* w_ih1 = (const float*)d_in[5];
    const float* w_hh1 = (const float*)d_in[6];
    const float* b_ih1 = (const float*)d_in[7];
    const float* b_hh1 = (const float*)d_in[8];
    const float* fc_w  = (const float*)d_in[9];
    const float* fc_b  = (const float*)d_in[10];
    float* out = (float*)d_out;

    char* ws = (char*)d_ws;
    uint* Wk0n  = (uint*)ws;                      // 262144 u
    uint* wih0n = Wk0n + 262144;                  // 12288 u
    uint* Wk1n  = wih0n + 12288;                  // 262144 u
    f16* wih1h  = (f16*)(Wk1n + 262144);          // 1048576 h = 2 MB
    float* bsum1 = (float*)(wih1h + 1048576);     // 2048 f
    float* hst  = bsum1 + 2048;                   // 65536 f
    float* cst  = hst + 65536;                    // 65536 f
    float* hsm  = cst + 65536;                    // 32768 f
    float* xp1  = hsm + 32768;                    // 2 x 16777216 f = 128 MB
    f16* out0h  = (f16*)(xp1 + 2 * XPS);          // 33554432 h = 64 MB

    k_prep<<<dim3(4096), dim3(256), 0, stream>>>(
        w_hh0, w_hh1, w_ih0, w_ih1, b_ih1, b_hh1,
        Wk0n, wih0n, Wk1n, wih1h, bsum1);

    k_rec0<<<dim3(64), dim3(512), 141312, stream>>>(
        Wk0n, wih0n, b_ih0, b_hh0, x, out0h, hst, cst);

    for (int j = 0; j <= NCHUNK; ++j) {
        k_pipe<<<dim3(192), dim3(512), 141312, stream>>>(
            j, Wk1n, out0h, wih1h, bsum1, xp1, hst, cst, hsm);
    }

    k_fc<<<dim3(64), dim3(32), 0, stream>>>(hsm, fc_w, fc_b, out);
}